// Round 10
// baseline (412.996 us; speedup 1.0000x reference)
//
#include <hip/hip_runtime.h>
#include <hip/hip_cooperative_groups.h>
#include <math.h>

namespace cg = cooperative_groups;

#define L     2048
#define NFFT  4096
#define NH    2049          // half-spectrum bins
#define UST   2052          // row stride (in float2) for half-spectrum rows
#define D     32
#define B     32
#define KU    3
#define CCH   64            // recurrence chunk length
#define NCH   32            // L / CCH

// skewed LDS physical address (pad 1 float per 32)
__device__ __forceinline__ int PHY(int i) { return i + (i >> 5); }
// base-4 digit reversal of a 12-bit index
__device__ __forceinline__ int REV4(int i) {
  int r2 = __brev(i) >> 20;
  return ((r2 & 0x555) << 1) | ((r2 >> 1) & 0x555);
}
// twiddle on the fly: exp(-2*pi*i*jr/4096) (SGN=+1) or its conjugate (SGN=-1)
template<int SGN>
__device__ __forceinline__ float2 twid(int jr) {
  float th = (float)jr * 1.5339807878856412e-3f;   // 2*pi/4096
  float s, c;
  __sincosf(th, &s, &c);
  return make_float2(c, SGN > 0 ? -s : s);
}

// ---------------------------------------------------------------- FFT cores
// Forward: 6 in-place radix-4 DIF stages. Natural in -> base4-digit-reversed out.
__device__ void dif6(float* sre, float* sim, int tid) {
  #pragma unroll
  for (int st = 0; st < 6; ++st) {
    const int shift = 10 - 2 * st;       // log2(q)
    const int q = 1 << shift;
    const int r = 1 << (2 * st);
    #pragma unroll
    for (int h = 0; h < 2; ++h) {
      const int idx = tid + h * 512;
      const int j = idx & (q - 1);
      const int g = idx >> shift;
      const int i0 = (g << (shift + 2)) + j;
      const int p0 = PHY(i0), p1 = PHY(i0 + q), p2 = PHY(i0 + 2 * q), p3 = PHY(i0 + 3 * q);
      float ax = sre[p0], ay = sim[p0], bx = sre[p1], by = sim[p1];
      float cx = sre[p2], cy = sim[p2], dx = sre[p3], dy = sim[p3];
      float t0x = ax + cx, t0y = ay + cy, t1x = ax - cx, t1y = ay - cy;
      float t2x = bx + dx, t2y = by + dy, t3x = bx - dx, t3y = by - dy;
      float2 w1 = twid<1>(j * r);
      float w2x = w1.x * w1.x - w1.y * w1.y, w2y = 2.f * w1.x * w1.y;
      float w3x = w2x * w1.x - w2y * w1.y, w3y = w2x * w1.y + w2y * w1.x;
      sre[p0] = t0x + t2x; sim[p0] = t0y + t2y;
      float u1x = t1x + t3y, u1y = t1y - t3x;              // t1 - i*t3
      sre[p1] = u1x * w1.x - u1y * w1.y; sim[p1] = u1x * w1.y + u1y * w1.x;
      float u2x = t0x - t2x, u2y = t0y - t2y;
      sre[p2] = u2x * w2x - u2y * w2y; sim[p2] = u2x * w2y + u2y * w2x;
      float u3x = t1x - t3y, u3y = t1y + t3x;              // t1 + i*t3
      sre[p3] = u3x * w3x - u3y * w3y; sim[p3] = u3x * w3y + u3y * w3x;
    }
    __syncthreads();
  }
}

// Inverse: 6 in-place radix-4 DIT stages. Digit-reversed in -> natural out.
__device__ void dit6(float* sre, float* sim, int tid) {
  #pragma unroll
  for (int st = 0; st < 6; ++st) {
    const int shift = 2 * st;
    const int q = 1 << shift;
    const int r = 1 << (10 - 2 * st);
    #pragma unroll
    for (int h = 0; h < 2; ++h) {
      const int idx = tid + h * 512;
      const int j = idx & (q - 1);
      const int g = idx >> shift;
      const int i0 = (g << (shift + 2)) + j;
      const int p0 = PHY(i0), p1 = PHY(i0 + q), p2 = PHY(i0 + 2 * q), p3 = PHY(i0 + 3 * q);
      float ax = sre[p0], ay = sim[p0], bx = sre[p1], by = sim[p1];
      float cx = sre[p2], cy = sim[p2], dx = sre[p3], dy = sim[p3];
      float2 w1 = twid<-1>(j * r);                         // conj twiddle
      float w2x = w1.x * w1.x - w1.y * w1.y, w2y = 2.f * w1.x * w1.y;
      float w3x = w2x * w1.x - w2y * w1.y, w3y = w2x * w1.y + w2y * w1.x;
      float bpx = bx * w1.x - by * w1.y, bpy = bx * w1.y + by * w1.x;
      float cpx = cx * w2x - cy * w2y,   cpy = cx * w2y + cy * w2x;
      float dpx = dx * w3x - dy * w3y,   dpy = dx * w3y + dy * w3x;
      float t0x = ax + cpx, t0y = ay + cpy, t1x = ax - cpx, t1y = ay - cpy;
      float t2x = bpx + dpx, t2y = bpy + dpy, t3x = bpx - dpx, t3y = bpy - dpy;
      sre[p0] = t0x + t2x; sim[p0] = t0y + t2y;
      sre[p1] = t1x - t3y; sim[p1] = t1y + t3x;            // t1 + i*t3
      sre[p2] = t0x - t2x; sim[p2] = t0y - t2y;
      sre[p3] = t1x + t3y; sim[p3] = t1y - t3x;            // t1 - i*t3
    }
    __syncthreads();
  }
}

// ---------------------------------------------------------------- forward FFT
// blocks 0..511: (p,b) = (blk>>5, blk&31) — same-b blocks share u cachelines
// AND the same blk%8 XCD class (L2 reuse of the strided u reads).
// FFT of z = u[b,:,2p] + i*u[b,:,2p+1]; unpack -> Ubuf rows b*32+2p, +1.
// blocks 512..527: eigvec pair p2; unpack + eigval^0.25 scale -> Vf rows.
__global__ __launch_bounds__(512) void k_fft_fwd(const float* __restrict__ u,
                                                 const float* __restrict__ eig_vecs,
                                                 const float* __restrict__ eig_vals,
                                                 float2* __restrict__ Ubuf,
                                                 float2* __restrict__ Vf) {
  __shared__ float sre[4224];
  __shared__ float sim[4224];
  const int blk = blockIdx.x;
  const int tid = threadIdx.x;
  if (blk < 512) {
    const int p = blk >> 5, b = blk & 31;
    const float* up = u + (size_t)b * L * D + 2 * p;
    for (int t = tid; t < L; t += 512) {
      float2 z = *(const float2*)(up + (size_t)t * D);
      int pp = PHY(t);
      sre[pp] = z.x; sim[pp] = z.y;
    }
  } else {
    const int p2 = blk - 512;
    for (int t = tid; t < L; t += 512) {
      int pp = PHY(t);
      sre[pp] = eig_vecs[(size_t)t * D + 2 * p2];
      sim[pp] = eig_vecs[(size_t)t * D + 2 * p2 + 1];
    }
  }
  for (int t = L + tid; t < NFFT; t += 512) {
    int pp = PHY(t);
    sre[pp] = 0.f; sim[pp] = 0.f;
  }
  __syncthreads();
  dif6(sre, sim, tid);
  // unpack: U_even = (A + conj(Ac))/2 ; U_odd = -i*(A - conj(Ac))/2
  if (blk < 512) {
    const int p = blk >> 5, b = blk & 31;
    float2* r0 = Ubuf + (size_t)(b * 32 + 2 * p) * UST;
    float2* r1 = r0 + UST;
    for (int f = tid; f <= 2048; f += 512) {
      int pa = PHY(REV4(f));
      int pc = PHY(REV4((NFFT - f) & (NFFT - 1)));
      float Ax = sre[pa], Ay = sim[pa];
      float Bx = sre[pc], By = -sim[pc];
      r0[f] = make_float2(0.5f * (Ax + Bx), 0.5f * (Ay + By));
      float Dx = Ax - Bx, Dy = Ay - By;
      r1[f] = make_float2(0.5f * Dy, -0.5f * Dx);
    }
  } else {
    const int p2 = blk - 512;
    const float sc0 = powf(eig_vals[2 * p2], 0.25f);
    const float sc1 = powf(eig_vals[2 * p2 + 1], 0.25f);
    float2* r0 = Vf + (size_t)(2 * p2) * UST;
    float2* r1 = r0 + UST;
    for (int f = tid; f <= 2048; f += 512) {
      int pa = PHY(REV4(f));
      int pc = PHY(REV4((NFFT - f) & (NFFT - 1)));
      float Ax = sre[pa], Ay = sim[pa];
      float Bx = sre[pc], By = -sim[pc];
      r0[f] = make_float2(0.5f * sc0 * (Ax + Bx), 0.5f * sc0 * (Ay + By));
      float Dx = Ax - Bx, Dy = Ay - By;
      r1[f] = make_float2(0.5f * sc1 * Dy, -0.5f * sc1 * Dx);
    }
  }
}

// ---------------------------------------------------------------- W build + Tc
// blocks 0..256: Wm[f,d,o] = sum_k Vf[k][f] * m_phi[(k*D+d)*D+o]  (8 f's each)
// block 257: Tc = T^64 where T = [[M0,M1],[I,0]] (6 squarings, 256 threads)
#define KWFT 8
__global__ __launch_bounds__(256) void k_w(const float2* __restrict__ Vf,
                                           const float* __restrict__ m_phi,
                                           const float* __restrict__ m_y,
                                           float2* __restrict__ Wm,
                                           float* __restrict__ Tc) {
  __shared__ float smem[8704];          // Ml[32][256] | A[64][68]+Bb[64][68]
  __shared__ float2 Vl[D][KWFT];
  const int tid = threadIdx.x;
  if (blockIdx.x == (NH + KWFT - 1) / KWFT) {     // Tc block
    float* A  = smem;                   // [64][68]
    float* Bb = smem + 4352;
    for (int idx = tid; idx < 64 * 64; idx += 256) {
      int r = idx >> 6, cc = idx & 63;
      float v;
      if (r < 32) v = m_y[(r * 2 + (cc >> 5)) * D + (cc & 31)];
      else        v = (cc == r - 32) ? 1.f : 0.f;
      A[r * 68 + cc] = v;
    }
    __syncthreads();
    const int r = tid >> 2, c0 = (tid & 3) << 4;
    for (int it = 0; it < 6; ++it) {
      float acc[16];
      #pragma unroll
      for (int j2 = 0; j2 < 16; ++j2) acc[j2] = 0.f;
      for (int i = 0; i < 64; ++i) {
        float a = A[r * 68 + i];
        #pragma unroll
        for (int j2 = 0; j2 < 16; ++j2) acc[j2] += a * A[i * 68 + c0 + j2];
      }
      __syncthreads();
      #pragma unroll
      for (int j2 = 0; j2 < 16; ++j2) Bb[r * 68 + c0 + j2] = acc[j2];
      __syncthreads();
      #pragma unroll
      for (int j2 = 0; j2 < 16; ++j2) A[r * 68 + c0 + j2] = Bb[r * 68 + c0 + j2];
      __syncthreads();
    }
    for (int idx = tid; idx < 64 * 64; idx += 256)
      Tc[idx] = A[(idx >> 6) * 68 + (idx & 63)];
    return;
  }
  const int f0 = blockIdx.x * KWFT;
  {
    int k = tid >> 3, ff = tid & 7;
    int f = f0 + ff;
    Vl[k][ff] = (f < NH) ? Vf[(size_t)k * UST + f] : make_float2(0.f, 0.f);
  }
  for (int c = 0; c < 4; ++c) {         // d-chunks: d = c*8 .. c*8+7
    __syncthreads();
    for (int i = tid; i < D * 256; i += 256)
      smem[i] = m_phi[(size_t)(i >> 8) * D * D + c * 256 + (i & 255)];
    __syncthreads();
    float m[D];
    #pragma unroll
    for (int k = 0; k < D; ++k) m[k] = smem[k * 256 + tid];
    const int d = c * 8 + (tid >> 5), o = tid & 31;
    #pragma unroll
    for (int ff = 0; ff < KWFT; ++ff) {
      int f = f0 + ff;
      if (f >= NH) break;
      float2 acc = make_float2(0.f, 0.f);
      #pragma unroll
      for (int k = 0; k < D; ++k) {
        float2 v = Vl[k][ff];
        acc.x += v.x * m[k];
        acc.y += v.y * m[k];
      }
      Wm[(size_t)f * D * D + d * D + o] = acc;
    }
  }
}

// ---------------------------------------------------------------- mix v5
// Q[b,o,f] = sum_d Ubuf[b,d,f] * Wm[f,d,o]; W in registers; batch-split grid.y.
#define FT 8
#define BC 8
__global__ __launch_bounds__(256) void k_mix(const float2* __restrict__ Ubuf,
                                             const float2* __restrict__ Wm,
                                             float2* __restrict__ Qbuf) {
  __shared__ float2 Ul[BC][D][FT];
  __shared__ float2 Qs[BC][D][FT];
  const int f0 = blockIdx.x * FT;
  const int bbase = blockIdx.y * 16;
  const int tid = threadIdx.x;
  const int o = tid & 31, fi = tid >> 5;
  const int f = f0 + fi;
  float2 Wr[D];
  if (f < NH) {
    const float2* wp = Wm + (size_t)f * D * D + o;
    #pragma unroll
    for (int d = 0; d < D; ++d) Wr[d] = wp[d * D];
  } else {
    #pragma unroll
    for (int d = 0; d < D; ++d) Wr[d] = make_float2(0.f, 0.f);
  }
  const int lf = tid & 7, row = tid >> 3;
  for (int b0 = bbase; b0 < bbase + 16; b0 += BC) {
    __syncthreads();
    #pragma unroll
    for (int it = 0; it < 8; ++it) {
      int r = row + it * 32;
      int bc = r >> 5, d = r & 31;
      int ff = f0 + lf;
      Ul[bc][d][lf] = (ff < NH)
          ? Ubuf[((size_t)(b0 + bc) * D + d) * UST + ff]
          : make_float2(0.f, 0.f);
    }
    __syncthreads();
    #pragma unroll
    for (int bc = 0; bc < BC; ++bc) {
      float ax = 0.f, ay = 0.f;
      #pragma unroll
      for (int d = 0; d < D; ++d) {
        float2 uu = Ul[bc][d][fi];
        float2 ww = Wr[d];
        ax += uu.x * ww.x - uu.y * ww.y;
        ay += uu.x * ww.y + uu.y * ww.x;
      }
      Qs[bc][o][(fi + o) & 7] = make_float2(ax, ay);
    }
    __syncthreads();
    #pragma unroll
    for (int it = 0; it < 8; ++it) {
      int r = row + it * 32;
      int bc = r >> 5, oo = r & 31;
      int ff = f0 + lf;
      if (ff < NH)
        Qbuf[((size_t)(b0 + bc) * D + oo) * UST + ff] = Qs[bc][oo][(lf + oo) & 7];
    }
  }
}

// ---------------------------------------------------------------- inverse FFT
// block (b*16+q): packed ifft of Y = Q[2q] + i*Q[2q+1]; Hermitian-extend +
// digit-reverse fused into the load. Output dT rows (b*32+2q), (b*32+2q+1).
__global__ __launch_bounds__(512) void k_ifft(const float2* __restrict__ Qbuf,
                                              float* __restrict__ dT) {
  __shared__ float sre[4224];
  __shared__ float sim[4224];
  const int blk = blockIdx.x;
  const int tid = threadIdx.x;
  const float2* r0 = Qbuf + (size_t)(2 * blk) * UST;
  const float2* r1 = r0 + UST;
  for (int f = tid; f <= 2048; f += 512) {
    float2 q1 = r0[f], q2 = r1[f];
    int pa = PHY(REV4(f));
    int pc = PHY(REV4((NFFT - f) & (NFFT - 1)));
    sre[pa] = q1.x - q2.y; sim[pa] = q1.y + q2.x;
    sre[pc] = q1.x + q2.y; sim[pc] = -q1.y + q2.x;
  }
  __syncthreads();
  dit6(sre, sim, tid);
  float* d0 = dT + (size_t)(2 * blk) * L;
  float* d1 = d0 + L;
  const float inv = 1.0f / (float)NFFT;
  for (int t = tid; t < L; t += 512) {
    int pp = PHY(t);
    d0[t] = sre[pp] * inv;
    d1[t] = sim[pp] * inv;
  }
}

// ---------------------------------------------------------------- fused scan
// Cooperative kernel, grid (NCH, B) x 64 threads, all blocks co-resident.
// Phase A: delta tile = dT tile + AR(u,m_u) built in LDS; zero-state scan;
//          write chunk tail states shat. One wave per block.
// Phase B (c==0 blocks): serial inter-chunk state scan per b -> sinb.
// Phase C: re-scan with true incoming state from the SAME LDS delta tile.
__global__ __launch_bounds__(64) void k_scan(const float* __restrict__ dT,
                                             const float* __restrict__ u,
                                             const float* __restrict__ m_u,
                                             const float* __restrict__ m_y,
                                             const float* __restrict__ Tc,
                                             float* __restrict__ shat,
                                             float* __restrict__ sinb,
                                             float* __restrict__ out) {
  __shared__ float Dl[CCH][D + 1];       // delta tile, persists A -> C
  __shared__ float ovl[4224];            // Us[66][32] (A) / TcT[64][65]+sb (B)
  __shared__ float yb[2][D];
  cg::grid_group grid = cg::this_grid();
  const int c = blockIdx.x, b = blockIdx.y;
  const int lane = threadIdx.x, o = lane & 31, h = lane >> 5;
  const int t0 = c * CCH;
  float m0[16], m1[16];
  #pragma unroll
  for (int i = 0; i < 16; ++i) {
    m0[i] = m_y[(o * 2 + 0) * D + h * 16 + i];
    m1[i] = m_y[(o * 2 + 1) * D + h * 16 + i];
  }
  float mu[KU][16];
  #pragma unroll
  for (int kk = 0; kk < KU; ++kk)
    #pragma unroll
    for (int i = 0; i < 16; ++i)
      mu[kk][i] = m_u[(size_t)(o * D + h * 16 + i) * KU + kk];
  // stage dT tile (coalesced per o-row)
  for (int idx = lane; idx < D * CCH; idx += 64) {
    int oo = idx >> 6, tt = idx & 63;
    Dl[tt][oo] = dT[((size_t)b * D + oo) * L + t0 + tt];
  }
  // stage u tile rows t0-2 .. t0+63
  float* Us = ovl;                       // [66][32]
  for (int idx = lane; idx < (CCH + 2) * D; idx += 64) {
    int j = idx >> 5, i = idx & 31;
    int t = t0 - 2 + j;
    Us[j * D + i] = (t >= 0) ? u[((size_t)b * L + t) * D + i] : 0.f;
  }
  __syncthreads();
  // AR add into Dl
  for (int tt = 0; tt < CCH; ++tt) {
    int t = t0 + tt;
    float acc = 0.f;
    #pragma unroll
    for (int kk = 0; kk < KU; ++kk) {
      if (t >= kk) {
        const float* ur = Us + (tt + 2 - kk) * D + h * 16;
        #pragma unroll
        for (int i = 0; i < 16; ++i) acc += mu[kk][i] * ur[i];
      }
    }
    acc += __shfl_xor(acc, 32);
    if (h == 0) Dl[tt][o] += acc;
  }
  // phase A: zero-state scan
  if (lane < D) { yb[0][lane] = 0.f; yb[1][lane] = 0.f; }
  __syncthreads();
  float ylast = 0.f, yprev = 0.f;
  for (int r = 0; r < CCH; ++r) {
    const float* y1 = yb[(r + 1) & 1];
    const float* y2 = yb[r & 1];
    float acc = 0.f;
    #pragma unroll
    for (int i = 0; i < 16; ++i)
      acc += m0[i] * y1[h * 16 + i] + m1[i] * y2[h * 16 + i];
    acc += __shfl_xor(acc, 32);
    float y = acc + Dl[r][o];
    __syncthreads();
    if (h == 0) yb[r & 1][o] = y;
    __syncthreads();
    yprev = ylast; ylast = y;
  }
  if (h == 0) {
    float* sp = shat + ((size_t)b * NCH + c) * 64;
    sp[o] = ylast;
    sp[32 + o] = yprev;
  }
  grid.sync();
  // phase B: inter-chunk state scan (blocks with c==0, one per b)
  if (c == 0) {
    float* TcT = ovl;                    // [64][65] transposed
    float* sb  = ovl + 64 * 65;
    for (int idx = lane; idx < 64 * 64; idx += 64) {
      int rr = idx >> 6, cc2 = idx & 63;
      TcT[cc2 * 65 + rr] = Tc[idx];
    }
    sb[lane] = 0.f;
    __syncthreads();
    for (int ch = 0; ch < NCH; ++ch) {
      sinb[((size_t)b * NCH + ch) * 64 + lane] = sb[lane];
      float acc = 0.f;
      #pragma unroll 8
      for (int i = 0; i < 64; ++i) acc += TcT[i * 65 + lane] * sb[i];
      acc += shat[((size_t)b * NCH + ch) * 64 + lane];
      __syncthreads();
      sb[lane] = acc;
      __syncthreads();
    }
  }
  grid.sync();
  // phase C: re-scan with true incoming state (Dl still resident)
  {
    const float* sp = sinb + ((size_t)b * NCH + c) * 64;
    if (lane < 32) yb[1][lane] = sp[lane];        // y_{-1}
    else           yb[0][lane - 32] = sp[lane];   // y_{-2}
    __syncthreads();
    float* op = out + ((size_t)b * L + t0) * D;
    for (int r = 0; r < CCH; ++r) {
      const float* y1 = yb[(r + 1) & 1];
      const float* y2 = yb[r & 1];
      float acc = 0.f;
      #pragma unroll
      for (int i = 0; i < 16; ++i)
        acc += m0[i] * y1[h * 16 + i] + m1[i] * y2[h * 16 + i];
      acc += __shfl_xor(acc, 32);
      float y = acc + Dl[r][o];
      __syncthreads();
      if (h == 0) { yb[r & 1][o] = y; op[r * D + o] = y; }
      __syncthreads();
    }
  }
}

// ---------------------------------------------------------------- launch
extern "C" void kernel_launch(void* const* d_in, const int* in_sizes, int n_in,
                              void* d_out, int out_size, void* d_ws, size_t ws_size,
                              hipStream_t stream) {
  const float* u        = (const float*)d_in[0];
  const float* eig_vals = (const float*)d_in[1];
  const float* eig_vecs = (const float*)d_in[2];
  const float* m_u      = (const float*)d_in[3];
  const float* m_phi    = (const float*)d_in[4];
  const float* m_y      = (const float*)d_in[5];
  float* out = (float*)d_out;

  char* ws = (char*)d_ws;
  size_t off = 0;
  auto alloc = [&](size_t bytes) -> void* {
    void* p = ws + off;
    off += bytes;
    off = (off + 255) & ~(size_t)255;
    return p;
  };
  float2* Vf   = (float2*)alloc((size_t)D * UST * sizeof(float2));        // 0.5 MB
  float2* Wm   = (float2*)alloc((size_t)NH * D * D * sizeof(float2));     // 16.8 MB
  float2* Ubuf = (float2*)alloc((size_t)B * D * UST * sizeof(float2));    // 16.8 MB
  float2* Qbuf = (float2*)alloc((size_t)B * D * UST * sizeof(float2));    // 16.8 MB
  float*  dT   = (float*)alloc((size_t)B * D * L * sizeof(float));        // 8 MB
  float*  Tc   = (float*)alloc(64 * 64 * sizeof(float));
  float*  shat = (float*)alloc((size_t)B * NCH * 64 * sizeof(float));
  float*  sinb = (float*)alloc((size_t)B * NCH * 64 * sizeof(float));

  k_fft_fwd<<<528, 512, 0, stream>>>(u, eig_vecs, eig_vals, Ubuf, Vf);
  k_w      <<<(NH + KWFT - 1) / KWFT + 1, 256, 0, stream>>>(Vf, m_phi, m_y, Wm, Tc);
  k_mix    <<<dim3((NH + FT - 1) / FT, 2), 256, 0, stream>>>(Ubuf, Wm, Qbuf);
  k_ifft   <<<B * 16, 512, 0, stream>>>(Qbuf, dT);

  void* args[] = { (void*)&dT, (void*)&u, (void*)&m_u, (void*)&m_y,
                   (void*)&Tc, (void*)&shat, (void*)&sinb, (void*)&out };
  hipLaunchCooperativeKernel((const void*)k_scan, dim3(NCH, B), dim3(64),
                             args, 0, stream);
}

// Round 11
// 256.997 us; speedup vs baseline: 1.6070x; 1.6070x over previous
//
#include <hip/hip_runtime.h>
#include <math.h>

#define L     2048
#define NFFT  4096
#define NH    2049          // half-spectrum bins
#define UST   2052          // row stride (in float2) for half-spectrum rows
#define D     32
#define B     32
#define KU    3
#define CCH   64            // recurrence chunk length
#define NCH   32            // L / CCH

// skewed LDS physical address (pad 1 float per 32)
__device__ __forceinline__ int PHY(int i) { return i + (i >> 5); }
// base-4 digit reversal of a 12-bit index
__device__ __forceinline__ int REV4(int i) {
  int r2 = __brev(i) >> 20;
  return ((r2 & 0x555) << 1) | ((r2 >> 1) & 0x555);
}
// twiddle on the fly: exp(-2*pi*i*jr/4096) (SGN=+1) or its conjugate (SGN=-1)
template<int SGN>
__device__ __forceinline__ float2 twid(int jr) {
  float th = (float)jr * 1.5339807878856412e-3f;   // 2*pi/4096
  float s, c;
  __sincosf(th, &s, &c);
  return make_float2(c, SGN > 0 ? -s : s);
}

// ---------------------------------------------------------------- FFT cores
// Forward: 6 in-place radix-4 DIF stages. Natural in -> base4-digit-reversed out.
__device__ void dif6(float* sre, float* sim, int tid) {
  #pragma unroll
  for (int st = 0; st < 6; ++st) {
    const int shift = 10 - 2 * st;       // log2(q)
    const int q = 1 << shift;
    const int r = 1 << (2 * st);
    #pragma unroll
    for (int h = 0; h < 2; ++h) {
      const int idx = tid + h * 512;
      const int j = idx & (q - 1);
      const int g = idx >> shift;
      const int i0 = (g << (shift + 2)) + j;
      const int p0 = PHY(i0), p1 = PHY(i0 + q), p2 = PHY(i0 + 2 * q), p3 = PHY(i0 + 3 * q);
      float ax = sre[p0], ay = sim[p0], bx = sre[p1], by = sim[p1];
      float cx = sre[p2], cy = sim[p2], dx = sre[p3], dy = sim[p3];
      float t0x = ax + cx, t0y = ay + cy, t1x = ax - cx, t1y = ay - cy;
      float t2x = bx + dx, t2y = by + dy, t3x = bx - dx, t3y = by - dy;
      float2 w1 = twid<1>(j * r);
      float w2x = w1.x * w1.x - w1.y * w1.y, w2y = 2.f * w1.x * w1.y;
      float w3x = w2x * w1.x - w2y * w1.y, w3y = w2x * w1.y + w2y * w1.x;
      sre[p0] = t0x + t2x; sim[p0] = t0y + t2y;
      float u1x = t1x + t3y, u1y = t1y - t3x;              // t1 - i*t3
      sre[p1] = u1x * w1.x - u1y * w1.y; sim[p1] = u1x * w1.y + u1y * w1.x;
      float u2x = t0x - t2x, u2y = t0y - t2y;
      sre[p2] = u2x * w2x - u2y * w2y; sim[p2] = u2x * w2y + u2y * w2x;
      float u3x = t1x - t3y, u3y = t1y + t3x;              // t1 + i*t3
      sre[p3] = u3x * w3x - u3y * w3y; sim[p3] = u3x * w3y + u3y * w3x;
    }
    __syncthreads();
  }
}

// Inverse: 6 in-place radix-4 DIT stages. Digit-reversed in -> natural out.
__device__ void dit6(float* sre, float* sim, int tid) {
  #pragma unroll
  for (int st = 0; st < 6; ++st) {
    const int shift = 2 * st;
    const int q = 1 << shift;
    const int r = 1 << (10 - 2 * st);
    #pragma unroll
    for (int h = 0; h < 2; ++h) {
      const int idx = tid + h * 512;
      const int j = idx & (q - 1);
      const int g = idx >> shift;
      const int i0 = (g << (shift + 2)) + j;
      const int p0 = PHY(i0), p1 = PHY(i0 + q), p2 = PHY(i0 + 2 * q), p3 = PHY(i0 + 3 * q);
      float ax = sre[p0], ay = sim[p0], bx = sre[p1], by = sim[p1];
      float cx = sre[p2], cy = sim[p2], dx = sre[p3], dy = sim[p3];
      float2 w1 = twid<-1>(j * r);                         // conj twiddle
      float w2x = w1.x * w1.x - w1.y * w1.y, w2y = 2.f * w1.x * w1.y;
      float w3x = w2x * w1.x - w2y * w1.y, w3y = w2x * w1.y + w2y * w1.x;
      float bpx = bx * w1.x - by * w1.y, bpy = bx * w1.y + by * w1.x;
      float cpx = cx * w2x - cy * w2y,   cpy = cx * w2y + cy * w2x;
      float dpx = dx * w3x - dy * w3y,   dpy = dx * w3y + dy * w3x;
      float t0x = ax + cpx, t0y = ay + cpy, t1x = ax - cpx, t1y = ay - cpy;
      float t2x = bpx + dpx, t2y = bpy + dpy, t3x = bpx - dpx, t3y = bpy - dpy;
      sre[p0] = t0x + t2x; sim[p0] = t0y + t2y;
      sre[p1] = t1x - t3y; sim[p1] = t1y + t3x;            // t1 + i*t3
      sre[p2] = t0x - t2x; sim[p2] = t0y - t2y;
      sre[p3] = t1x + t3y; sim[p3] = t1y - t3x;            // t1 - i*t3
    }
    __syncthreads();
  }
}

// ---------------------------------------------------------------- forward FFT
// blocks 0..511: (p,b) = (blk>>5, blk&31); FFT of z = u[b,:,2p] + i*u[b,:,2p+1];
// unpack -> Ubuf rows b*32+2p, +1. blocks 512..527: eigvec pair p2 -> Vf.
__global__ __launch_bounds__(512) void k_fft_fwd(const float* __restrict__ u,
                                                 const float* __restrict__ eig_vecs,
                                                 const float* __restrict__ eig_vals,
                                                 float2* __restrict__ Ubuf,
                                                 float2* __restrict__ Vf) {
  __shared__ float sre[4224];
  __shared__ float sim[4224];
  const int blk = blockIdx.x;
  const int tid = threadIdx.x;
  if (blk < 512) {
    const int p = blk >> 5, b = blk & 31;
    const float* up = u + (size_t)b * L * D + 2 * p;
    for (int t = tid; t < L; t += 512) {
      float2 z = *(const float2*)(up + (size_t)t * D);
      int pp = PHY(t);
      sre[pp] = z.x; sim[pp] = z.y;
    }
  } else {
    const int p2 = blk - 512;
    for (int t = tid; t < L; t += 512) {
      int pp = PHY(t);
      sre[pp] = eig_vecs[(size_t)t * D + 2 * p2];
      sim[pp] = eig_vecs[(size_t)t * D + 2 * p2 + 1];
    }
  }
  for (int t = L + tid; t < NFFT; t += 512) {
    int pp = PHY(t);
    sre[pp] = 0.f; sim[pp] = 0.f;
  }
  __syncthreads();
  dif6(sre, sim, tid);
  // unpack: U_even = (A + conj(Ac))/2 ; U_odd = -i*(A - conj(Ac))/2
  if (blk < 512) {
    const int p = blk >> 5, b = blk & 31;
    float2* r0 = Ubuf + (size_t)(b * 32 + 2 * p) * UST;
    float2* r1 = r0 + UST;
    for (int f = tid; f <= 2048; f += 512) {
      int pa = PHY(REV4(f));
      int pc = PHY(REV4((NFFT - f) & (NFFT - 1)));
      float Ax = sre[pa], Ay = sim[pa];
      float Bx = sre[pc], By = -sim[pc];
      r0[f] = make_float2(0.5f * (Ax + Bx), 0.5f * (Ay + By));
      float Dx = Ax - Bx, Dy = Ay - By;
      r1[f] = make_float2(0.5f * Dy, -0.5f * Dx);
    }
  } else {
    const int p2 = blk - 512;
    const float sc0 = powf(eig_vals[2 * p2], 0.25f);
    const float sc1 = powf(eig_vals[2 * p2 + 1], 0.25f);
    float2* r0 = Vf + (size_t)(2 * p2) * UST;
    float2* r1 = r0 + UST;
    for (int f = tid; f <= 2048; f += 512) {
      int pa = PHY(REV4(f));
      int pc = PHY(REV4((NFFT - f) & (NFFT - 1)));
      float Ax = sre[pa], Ay = sim[pa];
      float Bx = sre[pc], By = -sim[pc];
      r0[f] = make_float2(0.5f * sc0 * (Ax + Bx), 0.5f * sc0 * (Ay + By));
      float Dx = Ax - Bx, Dy = Ay - By;
      r1[f] = make_float2(0.5f * sc1 * Dy, -0.5f * sc1 * Dx);
    }
  }
}

// ---------------------------------------------------------------- W build + Tc
// blocks 0..256: Wm[f,d,o] = sum_k Vf[k][f] * m_phi[(k*D+d)*D+o]  (8 f's each)
// block 257: Tc = T^64 where T = [[M0,M1],[I,0]] (6 squarings, 256 threads)
#define KWFT 8
__global__ __launch_bounds__(256) void k_w(const float2* __restrict__ Vf,
                                           const float* __restrict__ m_phi,
                                           const float* __restrict__ m_y,
                                           float2* __restrict__ Wm,
                                           float* __restrict__ Tc) {
  __shared__ float smem[8704];          // Ml[32][256] | A[64][68]+Bb[64][68]
  __shared__ float2 Vl[D][KWFT];
  const int tid = threadIdx.x;
  if (blockIdx.x == (NH + KWFT - 1) / KWFT) {     // Tc block
    float* A  = smem;                   // [64][68]
    float* Bb = smem + 4352;
    for (int idx = tid; idx < 64 * 64; idx += 256) {
      int r = idx >> 6, cc = idx & 63;
      float v;
      if (r < 32) v = m_y[(r * 2 + (cc >> 5)) * D + (cc & 31)];
      else        v = (cc == r - 32) ? 1.f : 0.f;
      A[r * 68 + cc] = v;
    }
    __syncthreads();
    const int r = tid >> 2, c0 = (tid & 3) << 4;
    for (int it = 0; it < 6; ++it) {
      float acc[16];
      #pragma unroll
      for (int j2 = 0; j2 < 16; ++j2) acc[j2] = 0.f;
      for (int i = 0; i < 64; ++i) {
        float a = A[r * 68 + i];
        #pragma unroll
        for (int j2 = 0; j2 < 16; ++j2) acc[j2] += a * A[i * 68 + c0 + j2];
      }
      __syncthreads();
      #pragma unroll
      for (int j2 = 0; j2 < 16; ++j2) Bb[r * 68 + c0 + j2] = acc[j2];
      __syncthreads();
      #pragma unroll
      for (int j2 = 0; j2 < 16; ++j2) A[r * 68 + c0 + j2] = Bb[r * 68 + c0 + j2];
      __syncthreads();
    }
    for (int idx = tid; idx < 64 * 64; idx += 256)
      Tc[idx] = A[(idx >> 6) * 68 + (idx & 63)];
    return;
  }
  const int f0 = blockIdx.x * KWFT;
  {
    int k = tid >> 3, ff = tid & 7;
    int f = f0 + ff;
    Vl[k][ff] = (f < NH) ? Vf[(size_t)k * UST + f] : make_float2(0.f, 0.f);
  }
  for (int c = 0; c < 4; ++c) {         // d-chunks: d = c*8 .. c*8+7
    __syncthreads();
    for (int i = tid; i < D * 256; i += 256)
      smem[i] = m_phi[(size_t)(i >> 8) * D * D + c * 256 + (i & 255)];
    __syncthreads();
    float m[D];
    #pragma unroll
    for (int k = 0; k < D; ++k) m[k] = smem[k * 256 + tid];
    const int d = c * 8 + (tid >> 5), o = tid & 31;
    #pragma unroll
    for (int ff = 0; ff < KWFT; ++ff) {
      int f = f0 + ff;
      if (f >= NH) break;
      float2 acc = make_float2(0.f, 0.f);
      #pragma unroll
      for (int k = 0; k < D; ++k) {
        float2 v = Vl[k][ff];
        acc.x += v.x * m[k];
        acc.y += v.y * m[k];
      }
      Wm[(size_t)f * D * D + d * D + o] = acc;
    }
  }
}

// ---------------------------------------------------------------- mix v5
// Q[b,o,f] = sum_d Ubuf[b,d,f] * Wm[f,d,o]; W in registers; batch-split grid.y.
#define FT 8
#define BC 8
__global__ __launch_bounds__(256) void k_mix(const float2* __restrict__ Ubuf,
                                             const float2* __restrict__ Wm,
                                             float2* __restrict__ Qbuf) {
  __shared__ float2 Ul[BC][D][FT];
  __shared__ float2 Qs[BC][D][FT];
  const int f0 = blockIdx.x * FT;
  const int bbase = blockIdx.y * 16;
  const int tid = threadIdx.x;
  const int o = tid & 31, fi = tid >> 5;
  const int f = f0 + fi;
  float2 Wr[D];
  if (f < NH) {
    const float2* wp = Wm + (size_t)f * D * D + o;
    #pragma unroll
    for (int d = 0; d < D; ++d) Wr[d] = wp[d * D];
  } else {
    #pragma unroll
    for (int d = 0; d < D; ++d) Wr[d] = make_float2(0.f, 0.f);
  }
  const int lf = tid & 7, row = tid >> 3;
  for (int b0 = bbase; b0 < bbase + 16; b0 += BC) {
    __syncthreads();
    #pragma unroll
    for (int it = 0; it < 8; ++it) {
      int r = row + it * 32;
      int bc = r >> 5, d = r & 31;
      int ff = f0 + lf;
      Ul[bc][d][lf] = (ff < NH)
          ? Ubuf[((size_t)(b0 + bc) * D + d) * UST + ff]
          : make_float2(0.f, 0.f);
    }
    __syncthreads();
    #pragma unroll
    for (int bc = 0; bc < BC; ++bc) {
      float ax = 0.f, ay = 0.f;
      #pragma unroll
      for (int d = 0; d < D; ++d) {
        float2 uu = Ul[bc][d][fi];
        float2 ww = Wr[d];
        ax += uu.x * ww.x - uu.y * ww.y;
        ay += uu.x * ww.y + uu.y * ww.x;
      }
      Qs[bc][o][(fi + o) & 7] = make_float2(ax, ay);
    }
    __syncthreads();
    #pragma unroll
    for (int it = 0; it < 8; ++it) {
      int r = row + it * 32;
      int bc = r >> 5, oo = r & 31;
      int ff = f0 + lf;
      if (ff < NH)
        Qbuf[((size_t)(b0 + bc) * D + oo) * UST + ff] = Qs[bc][oo][(lf + oo) & 7];
    }
  }
}

// ---------------------------------------------------------------- inverse FFT
// block (b*16+q): packed ifft of Y = Q[2q] + i*Q[2q+1]; Hermitian-extend +
// digit-reverse fused into the load. Output dT rows (b*32+2q), (b*32+2q+1).
__global__ __launch_bounds__(512) void k_ifft(const float2* __restrict__ Qbuf,
                                              float* __restrict__ dT) {
  __shared__ float sre[4224];
  __shared__ float sim[4224];
  const int blk = blockIdx.x;
  const int tid = threadIdx.x;
  const float2* r0 = Qbuf + (size_t)(2 * blk) * UST;
  const float2* r1 = r0 + UST;
  for (int f = tid; f <= 2048; f += 512) {
    float2 q1 = r0[f], q2 = r1[f];
    int pa = PHY(REV4(f));
    int pc = PHY(REV4((NFFT - f) & (NFFT - 1)));
    sre[pa] = q1.x - q2.y; sim[pa] = q1.y + q2.x;
    sre[pc] = q1.x + q2.y; sim[pc] = -q1.y + q2.x;
  }
  __syncthreads();
  dit6(sre, sim, tid);
  float* d0 = dT + (size_t)(2 * blk) * L;
  float* d1 = d0 + L;
  const float inv = 1.0f / (float)NFFT;
  for (int t = tid; t < L; t += 512) {
    int pp = PHY(t);
    d0[t] = sre[pp] * inv;
    d1[t] = sim[pp] * inv;
  }
}

// ---------------------------------------------------------------- AR term
// delta[b,t,o] = dT[b,o,t] + sum_{k<=min(t,2)} sum_i m_u[o,i,k]*u[b,t-k,i]
#define TT 64
__global__ __launch_bounds__(256) void k_ar(const float* __restrict__ dT,
                                            const float* __restrict__ u,
                                            const float* __restrict__ m_u,
                                            float* __restrict__ delta) {
  __shared__ float Ds[D][TT + 1];
  __shared__ float Us[TT + 2][D];
  __shared__ float Mt[KU][D][D];      // [k][i][o]
  const int b = blockIdx.y;
  const int t0 = blockIdx.x * TT;
  const int tid = threadIdx.x;
  for (int idx = tid; idx < D * D * KU; idx += blockDim.x) {
    int k = idx % KU, i = (idx / KU) % D, o = idx / (KU * D);
    Mt[k][i][o] = m_u[idx];
  }
  for (int idx = tid; idx < D * TT; idx += blockDim.x) {
    int o = idx >> 6, tt = idx & 63;
    Ds[o][tt] = dT[((size_t)b * D + o) * L + t0 + tt];
  }
  for (int idx = tid; idx < (TT + 2) * D; idx += blockDim.x) {
    int j = idx >> 5, i = idx & 31;
    int t = t0 - 2 + j;
    Us[j][i] = (t >= 0) ? u[((size_t)b * L + t) * D + i] : 0.f;
  }
  __syncthreads();
  const int o = tid & 31, ts = tid >> 5;
  for (int tt = ts; tt < TT; tt += 8) {
    int t = t0 + tt;
    float acc = Ds[o][tt];
    #pragma unroll
    for (int k2 = 0; k2 < KU; ++k2) {
      if (t >= k2) {
        const float* ur = Us[tt + 2 - k2];
        #pragma unroll
        for (int i = 0; i < D; ++i) acc += Mt[k2][i][o] * ur[i];
      }
    }
    delta[((size_t)b * L + t) * D + o] = acc;
  }
}

// ---------------------------------------------------------------- scan chain
// Phase A: zero-state chunk response; emit shat[b,c] = [y_{C-1}; y_{C-2}]
// delta chunk staged in LDS so the serial chain has no global-load latency.
__global__ void k_scanA(const float* __restrict__ delta,
                        const float* __restrict__ m_y,
                        float* __restrict__ shat) {
  __shared__ float yb[2][D];
  __shared__ float Dl[CCH][D + 1];
  const int b = blockIdx.y, c = blockIdx.x;
  const int lane = threadIdx.x;            // 64 = one wave
  const int o = lane & 31, h = lane >> 5;
  float m0[16], m1[16];
  #pragma unroll
  for (int i = 0; i < 16; ++i) {
    m0[i] = m_y[(o * 2 + 0) * D + h * 16 + i];
    m1[i] = m_y[(o * 2 + 1) * D + h * 16 + i];
  }
  const float* dp = delta + ((size_t)b * L + c * CCH) * D;
  for (int j = lane; j < CCH * D / 4; j += 64) {
    float4 v = ((const float4*)dp)[j];
    int base = j * 4;
    int r = base >> 5, col = base & 31;
    Dl[r][col] = v.x; Dl[r][col + 1] = v.y;
    Dl[r][col + 2] = v.z; Dl[r][col + 3] = v.w;
  }
  if (lane < D) { yb[0][lane] = 0.f; yb[1][lane] = 0.f; }
  __syncthreads();
  float ylast = 0.f, yprev = 0.f;
  for (int r = 0; r < CCH; ++r) {
    const float* y1 = yb[(r + 1) & 1];
    const float* y2 = yb[r & 1];
    float acc = 0.f;
    #pragma unroll
    for (int i = 0; i < 16; ++i)
      acc += m0[i] * y1[h * 16 + i] + m1[i] * y2[h * 16 + i];
    acc += __shfl_xor(acc, 32);
    float y = acc + Dl[r][o];
    __syncthreads();
    if (h == 0) yb[r & 1][o] = y;
    __syncthreads();
    yprev = ylast; ylast = y;
  }
  if (h == 0) {
    float* sp = shat + ((size_t)b * NCH + c) * 64;
    sp[o] = ylast;
    sp[32 + o] = yprev;
  }
}

// Phase B: inter-chunk state scan, record incoming state per chunk.
__global__ void k_scanB(const float* __restrict__ Tc,
                        const float* __restrict__ shat,
                        float* __restrict__ sin_) {
  __shared__ float TcT[64][65];
  __shared__ float sb[64];
  const int b = blockIdx.x;
  const int r = threadIdx.x;               // 64
  for (int idx = r; idx < 64 * 64; idx += 64) {
    int rr = idx >> 6, cc = idx & 63;
    TcT[cc][rr] = Tc[idx];
  }
  sb[r] = 0.f;
  __syncthreads();
  for (int c = 0; c < NCH; ++c) {
    sin_[((size_t)b * NCH + c) * 64 + r] = sb[r];
    float acc = 0.f;
    #pragma unroll 8
    for (int i = 0; i < 64; ++i) acc += TcT[i][r] * sb[i];
    acc += shat[((size_t)b * NCH + c) * 64 + r];
    __syncthreads();
    sb[r] = acc;
    __syncthreads();
  }
}

// Phase C: re-run each chunk with true incoming state, write output.
__global__ void k_scanC(const float* __restrict__ delta,
                        const float* __restrict__ m_y,
                        const float* __restrict__ sin_,
                        float* __restrict__ out) {
  __shared__ float yb[2][D];
  __shared__ float Dl[CCH][D + 1];
  const int b = blockIdx.y, c = blockIdx.x;
  const int lane = threadIdx.x;
  const int o = lane & 31, h = lane >> 5;
  float m0[16], m1[16];
  #pragma unroll
  for (int i = 0; i < 16; ++i) {
    m0[i] = m_y[(o * 2 + 0) * D + h * 16 + i];
    m1[i] = m_y[(o * 2 + 1) * D + h * 16 + i];
  }
  const float* dp = delta + ((size_t)b * L + c * CCH) * D;
  for (int j = lane; j < CCH * D / 4; j += 64) {
    float4 v = ((const float4*)dp)[j];
    int base = j * 4;
    int r = base >> 5, col = base & 31;
    Dl[r][col] = v.x; Dl[r][col + 1] = v.y;
    Dl[r][col + 2] = v.z; Dl[r][col + 3] = v.w;
  }
  const float* sp = sin_ + ((size_t)b * NCH + c) * 64;
  if (lane < 32) yb[1][lane] = sp[lane];        // y_{-1}
  else           yb[0][lane - 32] = sp[lane];   // y_{-2}
  __syncthreads();
  float* op = out + ((size_t)b * L + c * CCH) * D;
  for (int r = 0; r < CCH; ++r) {
    const float* y1 = yb[(r + 1) & 1];
    const float* y2 = yb[r & 1];
    float acc = 0.f;
    #pragma unroll
    for (int i = 0; i < 16; ++i)
      acc += m0[i] * y1[h * 16 + i] + m1[i] * y2[h * 16 + i];
    acc += __shfl_xor(acc, 32);
    float y = acc + Dl[r][o];
    __syncthreads();
    if (h == 0) { yb[r & 1][o] = y; op[r * D + o] = y; }
    __syncthreads();
  }
}

// ---------------------------------------------------------------- launch
extern "C" void kernel_launch(void* const* d_in, const int* in_sizes, int n_in,
                              void* d_out, int out_size, void* d_ws, size_t ws_size,
                              hipStream_t stream) {
  const float* u        = (const float*)d_in[0];
  const float* eig_vals = (const float*)d_in[1];
  const float* eig_vecs = (const float*)d_in[2];
  const float* m_u      = (const float*)d_in[3];
  const float* m_phi    = (const float*)d_in[4];
  const float* m_y      = (const float*)d_in[5];
  float* out = (float*)d_out;

  char* ws = (char*)d_ws;
  size_t off = 0;
  auto alloc = [&](size_t bytes) -> void* {
    void* p = ws + off;
    off += bytes;
    off = (off + 255) & ~(size_t)255;
    return p;
  };
  float2* Vf   = (float2*)alloc((size_t)D * UST * sizeof(float2));        // 0.5 MB
  float2* Wm   = (float2*)alloc((size_t)NH * D * D * sizeof(float2));     // 16.8 MB
  float2* Ubuf = (float2*)alloc((size_t)B * D * UST * sizeof(float2));    // 16.8 MB
  float2* Qbuf = (float2*)alloc((size_t)B * D * UST * sizeof(float2));    // 16.8 MB
  float*  dT   = (float*)alloc((size_t)B * D * L * sizeof(float));        // 8 MB
  float*  Tc   = (float*)alloc(64 * 64 * sizeof(float));
  float*  shat = (float*)alloc((size_t)B * NCH * 64 * sizeof(float));
  float*  sinb = (float*)alloc((size_t)B * NCH * 64 * sizeof(float));
  // alias: delta reuses Ubuf (dead after k_mix)
  float* delta = (float*)Ubuf;

  k_fft_fwd<<<528, 512, 0, stream>>>(u, eig_vecs, eig_vals, Ubuf, Vf);
  k_w      <<<(NH + KWFT - 1) / KWFT + 1, 256, 0, stream>>>(Vf, m_phi, m_y, Wm, Tc);
  k_mix    <<<dim3((NH + FT - 1) / FT, 2), 256, 0, stream>>>(Ubuf, Wm, Qbuf);
  k_ifft   <<<B * 16, 512, 0, stream>>>(Qbuf, dT);
  k_ar     <<<dim3(L / TT, B), 256, 0, stream>>>(dT, u, m_u, delta);
  k_scanA  <<<dim3(NCH, B), 64, 0, stream>>>(delta, m_y, shat);
  k_scanB  <<<B, 64, 0, stream>>>(Tc, shat, sinb);
  k_scanC  <<<dim3(NCH, B), 64, 0, stream>>>(delta, m_y, sinb, out);
}